// Round 2
// baseline (547.816 us; speedup 1.0000x reference)
//
#include <hip/hip_runtime.h>
#include <stdint.h>

// Problem constants
#define BB 16384
#define DD 1024
#define HH 1024
#define OO 256
#define CC 8

typedef unsigned short u16;
typedef __attribute__((ext_vector_type(4))) unsigned short u16x4;
typedef __attribute__((ext_vector_type(8))) short bf16x8;
typedef __attribute__((ext_vector_type(4))) float f32x4;

__device__ __forceinline__ u16 f2bf(float f) {
    union { float f; uint32_t u; } v; v.f = f;
    const uint32_t u = v.u;
    return (u16)((u + 0x7FFFu + ((u >> 16) & 1u)) >> 16);  // RNE
}

// async global->LDS, 16B per lane (dest must be wave-uniform base + lane*16)
#define GLDS16(g, l)                                                                   \
    __builtin_amdgcn_global_load_lds((const __attribute__((address_space(1))) void*)(g), \
                                     (__attribute__((address_space(3))) void*)(l), 16, 0, 0)

// ---------------------------------------------------------------------------
// Transpose fp32 [nmat][R][Cc] -> bf16 [nmat][Cc][R]  (W -> W^T, K-contiguous)
// ---------------------------------------------------------------------------
__global__ __launch_bounds__(256)
void transpose_bf16_kernel(const float* __restrict__ src, u16* __restrict__ dst,
                           int R, int Cc)
{
    __shared__ float t[32][33];
    const int tid = threadIdx.x;
    const int mat = blockIdx.z;
    const int r0 = blockIdx.y * 32, c0 = blockIdx.x * 32;
    {
        const int rr = tid >> 3, c4 = (tid & 7) * 4;
        const float4 v = *(const float4*)(src + ((size_t)mat * R + r0 + rr) * Cc + c0 + c4);
        t[rr][c4 + 0] = v.x; t[rr][c4 + 1] = v.y; t[rr][c4 + 2] = v.z; t[rr][c4 + 3] = v.w;
    }
    __syncthreads();
    {
        const int cc = tid >> 3, k4 = (tid & 7) * 4;
        u16x4 o;
        o[0] = f2bf(t[k4 + 0][cc]);
        o[1] = f2bf(t[k4 + 1][cc]);
        o[2] = f2bf(t[k4 + 2][cc]);
        o[3] = f2bf(t[k4 + 3][cc]);
        *(u16x4*)(dst + ((size_t)mat * Cc + c0 + cc) * R + r0 + k4) = o;
    }
}

// ---------------------------------------------------------------------------
// Logits (fp32, exact routing) + x -> bf16 + per-class counts
// 1024 blocks x 16 rows; each wave computes 4 rows at once (16 loads in
// flight) and amortizes WcT LDS reads 4x. Reduction: 3-stage octet butterfly
// on 32 accs -> class select -> 3-stage scalar butterfly -> argmax butterfly.
// ---------------------------------------------------------------------------
__global__ __launch_bounds__(256, 4)
void logits_kernel(const float* __restrict__ x, const float* __restrict__ Wc,
                   const float* __restrict__ bc, float* __restrict__ logits_out,
                   u16* __restrict__ x_bf16, int* __restrict__ class_idx,
                   int* __restrict__ counts)
{
    __shared__ float WcT[CC][DD];  // 32 KB, transposed classifier
    const int tid = threadIdx.x;
    #pragma unroll
    for (int j = 0; j < 8; ++j) {
        const int f = tid + 256 * j;                 // float4 index into Wc [D][C]
        const float4 v = ((const float4*)Wc)[f];
        const int d = f >> 1, c = (f & 1) * 4;       // 4 elems share d (C=8)
        WcT[c + 0][d] = v.x; WcT[c + 1][d] = v.y; WcT[c + 2][d] = v.z; WcT[c + 3][d] = v.w;
    }
    __syncthreads();

    const int lane = tid & 63, wv = tid >> 6;
    const int row0 = blockIdx.x * 16 + wv * 4;

    // ---- issue all 16 row loads up-front (MLP) ----
    float4 xv[4][4];
    #pragma unroll
    for (int r = 0; r < 4; ++r) {
        const float4* xr = (const float4*)(x + (size_t)(row0 + r) * DD);
        #pragma unroll
        for (int j = 0; j < 4; ++j) xv[r][j] = xr[lane + 64 * j];
    }
    // ---- x -> bf16 stores ----
    #pragma unroll
    for (int r = 0; r < 4; ++r) {
        u16* xb = x_bf16 + (size_t)(row0 + r) * DD;
        #pragma unroll
        for (int j = 0; j < 4; ++j) {
            const float4 v = xv[r][j];
            u16x4 o; o[0] = f2bf(v.x); o[1] = f2bf(v.y); o[2] = f2bf(v.z); o[3] = f2bf(v.w);
            *(u16x4*)(xb + 4 * (lane + 64 * j)) = o;
        }
    }
    // ---- FMA: one WcT read feeds 4 rows ----
    float acc[4][8];
    #pragma unroll
    for (int r = 0; r < 4; ++r)
        #pragma unroll
        for (int c = 0; c < 8; ++c) acc[r][c] = 0.f;
    #pragma unroll
    for (int j = 0; j < 4; ++j) {
        const int f = lane + 64 * j;
        #pragma unroll
        for (int c = 0; c < 8; ++c) {
            const float4 w = *(const float4*)&WcT[c][4 * f];
            #pragma unroll
            for (int r = 0; r < 4; ++r)
                acc[r][c] += xv[r][j].x * w.x + xv[r][j].y * w.y
                           + xv[r][j].z * w.z + xv[r][j].w * w.w;
        }
    }

    // ---- phase A: reduce over lane octets (bits 3..5), all 32 values ----
    #pragma unroll
    for (int off = 8; off < 64; off <<= 1)
        #pragma unroll
        for (int r = 0; r < 4; ++r)
            #pragma unroll
            for (int c = 0; c < 8; ++c)
                acc[r][c] += __shfl_xor(acc[r][c], off, 64);
    // acc[r][c] now = partial sum over lanes { l : l === lane (mod 8) }

    // ---- phase B: lane owns class (lane>>3); sum the 8 octet groups ----
    const int cls = lane >> 3;
    const float bcv = bc[cls];
    float s[4];
    #pragma unroll
    for (int r = 0; r < 4; ++r) {
        float v = acc[r][0];
        #pragma unroll
        for (int c = 1; c < 8; ++c) v = (cls == c) ? acc[r][c] : v;
        s[r] = v;
    }
    #pragma unroll
    for (int off = 1; off < 8; off <<= 1)
        #pragma unroll
        for (int r = 0; r < 4; ++r) s[r] += __shfl_xor(s[r], off, 64);
    #pragma unroll
    for (int r = 0; r < 4; ++r) s[r] += bcv;

    // ---- write logits (one lane per (row, class)) ----
    #pragma unroll
    for (int r = 0; r < 4; ++r)
        if ((lane & 7) == 0) logits_out[(size_t)(row0 + r) * CC + cls] = s[r];

    // ---- argmax butterfly over classes (bits 3..5), first-occurrence ties ----
    int idx[4] = {cls, cls, cls, cls};
    #pragma unroll
    for (int off = 8; off < 64; off <<= 1) {
        #pragma unroll
        for (int r = 0; r < 4; ++r) {
            const float ov = __shfl_xor(s[r], off, 64);
            const int oi = __shfl_xor(idx[r], off, 64);
            const bool take = (ov > s[r]) || (ov == s[r] && oi < idx[r]);
            s[r] = take ? ov : s[r];
            idx[r] = take ? oi : idx[r];
        }
    }
    if (lane == 0) {
        #pragma unroll
        for (int r = 0; r < 4; ++r) {
            class_idx[row0 + r] = idx[r];
            atomicAdd(&counts[idx[r]], 1);
        }
    }
}

// ---------------------------------------------------------------------------
// Per-class padded prefix offsets (pad to 128-row tiles)
// ---------------------------------------------------------------------------
__global__ void offsets_kernel(const int* __restrict__ counts, int* __restrict__ offsets)
{
    if (threadIdx.x == 0 && blockIdx.x == 0) {
        int o = 0; offsets[0] = 0;
        #pragma unroll
        for (int c = 0; c < CC; ++c) { o += (counts[c] + 127) & ~127; offsets[c + 1] = o; }
    }
}

// ---------------------------------------------------------------------------
// Scatter row ids into per-class segments (pad slots stay -1)
// ---------------------------------------------------------------------------
__global__ __launch_bounds__(256)
void scatter_kernel(const int* __restrict__ class_idx, const int* __restrict__ offsets,
                    int* __restrict__ cursors, int* __restrict__ rowidx)
{
    const int r = blockIdx.x * 256 + threadIdx.x;
    const int c = class_idx[r];
    const int slot = atomicAdd(&cursors[c], 1);
    rowidx[offsets[c] + slot] = r;
}

// ---------------------------------------------------------------------------
// Routed GEMM: out[m][n] = act(A[m][:] . W_c[:][n] + bias_c[n])
// BM=BN=128, BK=32, 256 threads / 4 waves (64x64 per wave), K=1024 fixed.
// A: bf16 [rows][1024] (gathered by rowidx for layer 1, padded-compact after).
// W: bf16 [C][N][K] (pre-transposed) -> B-operand staging identical to A.
// m97-style: global_load_lds w=16 staging, 2 barriers per K-step.
// ---------------------------------------------------------------------------
template<int NSTRIDE, bool GATHER_A, bool RELU, bool FINAL>
__global__ __launch_bounds__(256)
void gemm_kernel(const u16* __restrict__ Abase, const u16* __restrict__ Wbase,
                 size_t wclass_stride, const float* __restrict__ bias_base,
                 int bias_stride, const int* __restrict__ offsets,
                 const int* __restrict__ rowidx, u16* __restrict__ Hout,
                 float* __restrict__ Fout)
{
    __shared__ u16 sA[128 * 32];   // [row][k] bf16, 8 KB
    __shared__ u16 sB[128 * 32];   // [n][k] bf16, 8 KB
    const int tid = threadIdx.x;
    const int m0 = blockIdx.x * 128;
    if (m0 >= offsets[CC]) return;            // beyond padded total
    int c = 0;
    while (m0 >= offsets[c + 1]) ++c;         // tile -> class (offsets are 128-multiples)
    const int n0 = blockIdx.y * 128;

    // staging: 512 x 16B chunks per 8KB tile, 2 rounds of 256 threads
    const int srow = tid >> 2;                // 0..63
    const int kc8 = (tid & 3) * 8;            // k-chunk (8 bf16 = 16B)
    int sa0 = m0 + srow, sa1 = m0 + srow + 64;
    if (GATHER_A) {
        const int g0 = rowidx[sa0]; sa0 = (g0 < 0) ? 0 : g0;
        const int g1 = rowidx[sa1]; sa1 = (g1 < 0) ? 0 : g1;
    }
    const u16* gA0 = Abase + (size_t)sa0 * 1024 + kc8;
    const u16* gA1 = Abase + (size_t)sa1 * 1024 + kc8;
    const u16* Wcl = Wbase + (size_t)c * wclass_stride;
    const u16* gB0 = Wcl + (size_t)(n0 + srow) * 1024 + kc8;
    const u16* gB1 = Wcl + (size_t)(n0 + srow + 64) * 1024 + kc8;
    u16* lA0 = sA + tid * 8;
    u16* lA1 = sA + 2048 + tid * 8;
    u16* lB0 = sB + tid * 8;
    u16* lB1 = sB + 2048 + tid * 8;

    const int lane = tid & 63, wv = tid >> 6;
    const int wm = (wv & 1) * 64, wn = (wv >> 1) * 64;
    const int lr = lane & 15, lg = lane >> 4;
    const u16* fA = sA + (wm + lr) * 32 + lg * 8;  // A[m=lr][k chunk lg], b128
    const u16* fB = sB + (wn + lr) * 32 + lg * 8;  // W^T[n=lr][k chunk lg], b128

    f32x4 acc[4][4];
    #pragma unroll
    for (int i = 0; i < 4; ++i)
        #pragma unroll
        for (int j = 0; j < 4; ++j)
            acc[i][j] = (f32x4){0.f, 0.f, 0.f, 0.f};

    for (int kt = 0; kt < 32; ++kt) {
        const int kb = kt * 32;   // elems (64B per row per step)
        GLDS16(gA0 + kb, lA0);
        GLDS16(gA1 + kb, lA1);
        GLDS16(gB0 + kb, lB0);
        GLDS16(gB1 + kb, lB1);
        __syncthreads();          // compiler drains vmcnt before barrier
        bf16x8 af[4], bfr[4];
        #pragma unroll
        for (int i = 0; i < 4; ++i) {
            af[i]  = *(const bf16x8*)(fA + i * 16 * 32);
            bfr[i] = *(const bf16x8*)(fB + i * 16 * 32);
        }
        #pragma unroll
        for (int mi = 0; mi < 4; ++mi)
            #pragma unroll
            for (int ni = 0; ni < 4; ++ni)
                acc[mi][ni] = __builtin_amdgcn_mfma_f32_16x16x32_bf16(
                    af[mi], bfr[ni], acc[mi][ni], 0, 0, 0);
        __syncthreads();
    }

    // epilogue: C/D layout col=lane&15, row=(lane>>4)*4+reg (m89-verified)
    const float* bp = bias_base + (size_t)c * bias_stride + n0 + wn + lr;
    #pragma unroll
    for (int ni = 0; ni < 4; ++ni) {
        const float bv = bp[ni * 16];
        const int col = n0 + wn + ni * 16 + lr;
        #pragma unroll
        for (int mi = 0; mi < 4; ++mi) {
            const int rb = m0 + wm + mi * 16 + lg * 4;
            #pragma unroll
            for (int q = 0; q < 4; ++q) {
                float v = acc[mi][ni][q] + bv;
                if (RELU) v = v > 0.f ? v : 0.f;
                if (FINAL) {
                    const int orow = rowidx[rb + q];
                    if (orow >= 0) Fout[(size_t)orow * NSTRIDE + col] = v;
                } else {
                    Hout[(size_t)(rb + q) * NSTRIDE + col] = f2bf(v);
                }
            }
        }
    }
}

// ---------------------------------------------------------------------------
extern "C" void kernel_launch(void* const* d_in, const int* in_sizes, int n_in,
                              void* d_out, int out_size, void* d_ws, size_t ws_size,
                              hipStream_t stream)
{
    const float* x  = (const float*)d_in[0];
    const float* Wc = (const float*)d_in[1];
    const float* bc = (const float*)d_in[2];
    const float* W1 = (const float*)d_in[3];
    const float* b1 = (const float*)d_in[4];
    const float* W2 = (const float*)d_in[5];
    const float* b2 = (const float*)d_in[6];
    const float* Wo = (const float*)d_in[7];
    const float* bo = (const float*)d_in[8];
    float* out    = (float*)d_out;                 // [B][O]
    float* logits = out + (size_t)BB * OO;         // [B][C]

    char* ws = (char*)d_ws;
    constexpr size_t PADMAX = BB + CC * 128;       // 17408 padded rows max
    int* counts    = (int*)(ws + 0);
    int* cursors   = (int*)(ws + 32);
    int* offsets   = (int*)(ws + 64);
    int* class_idx = (int*)(ws + 256);
    int* rowidx    = (int*)(ws + 256 + (size_t)BB * 4);
    u16* x_bf16    = (u16*)(ws + 256 + (size_t)BB * 4 + PADMAX * 4);
    u16* hA  = x_bf16 + (size_t)BB * DD;
    u16* hB  = hA + PADMAX * HH;
    u16* W1T = hB + PADMAX * HH;                    // [C][H][D]
    u16* W2T = W1T + (size_t)CC * DD * HH;          // [C][2][H][H] (N-major per mat)
    u16* WoT = W2T + (size_t)CC * 2 * HH * HH;      // [C][O][H]
    // total ws use ~160 MB

    hipMemsetAsync(ws, 0, 128, stream);             // counts + cursors
    hipMemsetAsync(rowidx, 0xFF, PADMAX * 4, stream);  // pad slots = -1

    transpose_bf16_kernel<<<dim3(32, 32, 8),  256, 0, stream>>>(W1, W1T, DD, HH);
    transpose_bf16_kernel<<<dim3(32, 32, 16), 256, 0, stream>>>(W2, W2T, HH, HH);
    transpose_bf16_kernel<<<dim3(8, 32, 8),   256, 0, stream>>>(Wo, WoT, HH, OO);

    logits_kernel<<<BB / 16, 256, 0, stream>>>(x, Wc, bc, logits, x_bf16, class_idx, counts);
    offsets_kernel<<<1, 64, 0, stream>>>(counts, offsets);
    scatter_kernel<<<BB / 256, 256, 0, stream>>>(class_idx, offsets, cursors, rowidx);

    constexpr int MT = BB / 128 + CC;  // 136 M-tiles (covers worst-case padding)
    gemm_kernel<HH, true,  true,  false><<<dim3(MT, 8), 256, 0, stream>>>(
        x_bf16, W1T, (size_t)DD * HH, b1, HH, offsets, rowidx, hA, nullptr);
    gemm_kernel<HH, false, true,  false><<<dim3(MT, 8), 256, 0, stream>>>(
        hA, W2T, (size_t)2 * HH * HH, b2, 2 * HH, offsets, rowidx, hB, nullptr);
    gemm_kernel<HH, false, true,  false><<<dim3(MT, 8), 256, 0, stream>>>(
        hB, W2T + (size_t)HH * HH, (size_t)2 * HH * HH, b2 + HH, 2 * HH, offsets, rowidx, hA, nullptr);
    gemm_kernel<OO, false, false, true ><<<dim3(MT, 2), 256, 0, stream>>>(
        hA, WoT, (size_t)OO * HH, bo, OO, offsets, rowidx, nullptr, out);
}

// Round 3
// 299.186 us; speedup vs baseline: 1.8310x; 1.8310x over previous
//
#include <hip/hip_runtime.h>
#include <stdint.h>

// Problem constants
#define BB 16384
#define DD 1024
#define HH 1024
#define OO 256
#define CC 8

typedef unsigned short u16;
typedef __attribute__((ext_vector_type(4))) unsigned short u16x4;
typedef __attribute__((ext_vector_type(8))) short bf16x8;
typedef __attribute__((ext_vector_type(4))) float f32x4;

__device__ __forceinline__ u16 f2bf(float f) {
    union { float f; uint32_t u; } v; v.f = f;
    const uint32_t u = v.u;
    return (u16)((u + 0x7FFFu + ((u >> 16) & 1u)) >> 16);  // RNE
}

// async global->LDS, 16B per lane (dest must be wave-uniform base + lane*16)
#define GLDS16(g, l)                                                                   \
    __builtin_amdgcn_global_load_lds((const __attribute__((address_space(1))) void*)(g), \
                                     (__attribute__((address_space(3))) void*)(l), 16, 0, 0)

// ---------------------------------------------------------------------------
// Transpose fp32 [nmat][R][Cc] -> bf16 [nmat][Cc][R]  (W -> W^T, K-contiguous)
// ---------------------------------------------------------------------------
__global__ __launch_bounds__(256)
void transpose_bf16_kernel(const float* __restrict__ src, u16* __restrict__ dst,
                           int R, int Cc)
{
    __shared__ float t[32][33];
    const int tid = threadIdx.x;
    const int mat = blockIdx.z;
    const int r0 = blockIdx.y * 32, c0 = blockIdx.x * 32;
    {
        const int rr = tid >> 3, c4 = (tid & 7) * 4;
        const float4 v = *(const float4*)(src + ((size_t)mat * R + r0 + rr) * Cc + c0 + c4);
        t[rr][c4 + 0] = v.x; t[rr][c4 + 1] = v.y; t[rr][c4 + 2] = v.z; t[rr][c4 + 3] = v.w;
    }
    __syncthreads();
    {
        const int cc = tid >> 3, k4 = (tid & 7) * 4;
        u16x4 o;
        o[0] = f2bf(t[k4 + 0][cc]);
        o[1] = f2bf(t[k4 + 1][cc]);
        o[2] = f2bf(t[k4 + 2][cc]);
        o[3] = f2bf(t[k4 + 3][cc]);
        *(u16x4*)(dst + ((size_t)mat * Cc + c0 + cc) * R + r0 + k4) = o;
    }
}

// ---------------------------------------------------------------------------
// Logits (fp32, exact routing) + x -> bf16 + per-block class histogram.
// 1024 blocks x 16 rows, 4 rows/wave processed in 2-row batches (keeps VGPR
// ~90, no spills). ZERO global atomics: per-block histogram via ballots.
// ---------------------------------------------------------------------------
__global__ __launch_bounds__(256)
void logits_kernel(const float* __restrict__ x, const float* __restrict__ Wc,
                   const float* __restrict__ bc, float* __restrict__ logits_out,
                   u16* __restrict__ x_bf16, int* __restrict__ class_idx,
                   int* __restrict__ hist)
{
    __shared__ float WcT[CC][DD];  // 32 KB, transposed classifier
    __shared__ int clsarr[16];
    const int tid = threadIdx.x;
    #pragma unroll
    for (int j = 0; j < 8; ++j) {
        const int f = tid + 256 * j;                 // float4 index into Wc [D][C]
        const float4 v = ((const float4*)Wc)[f];
        const int d = f >> 1, c = (f & 1) * 4;       // 4 elems share d (C=8)
        WcT[c + 0][d] = v.x; WcT[c + 1][d] = v.y; WcT[c + 2][d] = v.z; WcT[c + 3][d] = v.w;
    }
    __syncthreads();

    const int lane = tid & 63, wv = tid >> 6;
    const int row0 = blockIdx.x * 16 + wv * 4;

    float acc[4][8];
    #pragma unroll
    for (int r = 0; r < 4; ++r)
        #pragma unroll
        for (int c = 0; c < 8; ++c) acc[r][c] = 0.f;

    // ---- 2 rows per batch: 8 independent loads in flight, 32 transient regs
    #pragma unroll
    for (int p = 0; p < 2; ++p) {
        float4 xv[2][4];
        #pragma unroll
        for (int rr = 0; rr < 2; ++rr) {
            const float4* xr = (const float4*)(x + (size_t)(row0 + 2 * p + rr) * DD);
            #pragma unroll
            for (int j = 0; j < 4; ++j) xv[rr][j] = xr[lane + 64 * j];
        }
        #pragma unroll
        for (int rr = 0; rr < 2; ++rr) {
            u16* xb = x_bf16 + (size_t)(row0 + 2 * p + rr) * DD;
            #pragma unroll
            for (int j = 0; j < 4; ++j) {
                const float4 v = xv[rr][j];
                u16x4 o; o[0] = f2bf(v.x); o[1] = f2bf(v.y); o[2] = f2bf(v.z); o[3] = f2bf(v.w);
                *(u16x4*)(xb + 4 * (lane + 64 * j)) = o;
            }
        }
        #pragma unroll
        for (int j = 0; j < 4; ++j) {
            const int f = lane + 64 * j;
            #pragma unroll
            for (int c = 0; c < 8; ++c) {
                const float4 w = *(const float4*)&WcT[c][4 * f];
                #pragma unroll
                for (int rr = 0; rr < 2; ++rr)
                    acc[2 * p + rr][c] += xv[rr][j].x * w.x + xv[rr][j].y * w.y
                                        + xv[rr][j].z * w.z + xv[rr][j].w * w.w;
            }
        }
    }

    // ---- phase A: reduce over lane octets (bits 3..5), all 32 values ----
    #pragma unroll
    for (int off = 8; off < 64; off <<= 1)
        #pragma unroll
        for (int r = 0; r < 4; ++r)
            #pragma unroll
            for (int c = 0; c < 8; ++c)
                acc[r][c] += __shfl_xor(acc[r][c], off, 64);

    // ---- phase B: lane owns class (lane>>3); sum the 8 octet groups ----
    const int cls = lane >> 3;
    const float bcv = bc[cls];
    float s[4];
    #pragma unroll
    for (int r = 0; r < 4; ++r) {
        float v = acc[r][0];
        #pragma unroll
        for (int c = 1; c < 8; ++c) v = (cls == c) ? acc[r][c] : v;
        s[r] = v;
    }
    #pragma unroll
    for (int off = 1; off < 8; off <<= 1)
        #pragma unroll
        for (int r = 0; r < 4; ++r) s[r] += __shfl_xor(s[r], off, 64);
    #pragma unroll
    for (int r = 0; r < 4; ++r) s[r] += bcv;

    // ---- write logits (one lane per (row, class)) ----
    #pragma unroll
    for (int r = 0; r < 4; ++r)
        if ((lane & 7) == 0) logits_out[(size_t)(row0 + r) * CC + cls] = s[r];

    // ---- argmax butterfly over classes (bits 3..5), first-occurrence ties ----
    int idx[4] = {cls, cls, cls, cls};
    #pragma unroll
    for (int off = 8; off < 64; off <<= 1) {
        #pragma unroll
        for (int r = 0; r < 4; ++r) {
            const float ov = __shfl_xor(s[r], off, 64);
            const int oi = __shfl_xor(idx[r], off, 64);
            const bool take = (ov > s[r]) || (ov == s[r] && oi < idx[r]);
            s[r] = take ? ov : s[r];
            idx[r] = take ? oi : idx[r];
        }
    }
    if (lane == 0) {
        #pragma unroll
        for (int r = 0; r < 4; ++r) {
            class_idx[row0 + r] = idx[r];
            clsarr[wv * 4 + r] = idx[r];
        }
    }
    __syncthreads();
    // ---- per-block histogram via ballots (wave 0 only, no atomics) ----
    if (tid < 64) {
        const int myc = (tid < 16) ? clsarr[tid] : -1;
        int h = 0;
        #pragma unroll
        for (int cc = 0; cc < 8; ++cc) {
            const int p = __popcll(__ballot(myc == cc));
            h = (tid == cc) ? p : h;
        }
        if (tid < 8) hist[blockIdx.x * 8 + tid] = h;
    }
}

// ---------------------------------------------------------------------------
// Single-block scan: per-class totals -> padded offsets + per-block bases.
// Thread t: class c = t>>5, group lane g = t&31 covers 32 logits-blocks.
// ---------------------------------------------------------------------------
__global__ __launch_bounds__(256)
void scan_kernel(const int* __restrict__ hist, int* __restrict__ offsets,
                 int* __restrict__ bb)
{
    const int t = threadIdx.x, c = t >> 5, g = t & 31;
    int sum = 0;
    #pragma unroll 4
    for (int i = 0; i < 32; ++i) sum += hist[(g * 32 + i) * 8 + c];
    int inc = sum;  // inclusive scan over g within the 32-lane group
    #pragma unroll
    for (int d = 1; d < 32; d <<= 1) {
        const int v = __shfl_up(inc, d, 32);
        if (g >= d) inc += v;
    }
    __shared__ int tot[8], offL[9];
    if (g == 31) tot[c] = inc;
    __syncthreads();
    if (t == 0) {
        int o = 0; offL[0] = 0; offsets[0] = 0;
        #pragma unroll
        for (int c8 = 0; c8 < 8; ++c8) {
            o += (tot[c8] + 127) & ~127;
            offL[c8 + 1] = o; offsets[c8 + 1] = o;
        }
    }
    __syncthreads();
    int base = offL[c] + (inc - sum);  // exclusive prefix over groups
    #pragma unroll 4
    for (int i = 0; i < 32; ++i) {
        const int b = g * 32 + i;
        bb[b * 8 + c] = base;
        base += hist[b * 8 + c];
    }
}

// ---------------------------------------------------------------------------
// Scatter row ids into per-class segments — atomic-free via ballot ranking.
// rank = # earlier rows in my 16-row logits-block with my class.
// ---------------------------------------------------------------------------
__global__ __launch_bounds__(256)
void scatter_kernel(const int* __restrict__ class_idx, const int* __restrict__ bb,
                    int* __restrict__ rowidx)
{
    const int r = blockIdx.x * 256 + threadIdx.x;
    const int c = class_idx[r];
    const int lane = threadIdx.x & 63;
    const int gl = lane & ~15;  // base lane of my 16-row group
    const unsigned long long before = (1ull << lane) - (1ull << gl);
    int rank = 0;
    #pragma unroll
    for (int cc = 0; cc < 8; ++cc) {
        const unsigned long long m = __ballot(c == cc);
        const int p = __popcll(m & before);
        rank = (c == cc) ? p : rank;
    }
    rowidx[bb[(r >> 4) * 8 + c] + rank] = r;
}

// ---------------------------------------------------------------------------
// Routed GEMM: out[m][n] = act(A[m][:] . W_c[:][n] + bias_c[n])
// BM=BN=128, BK=32, 256 threads / 4 waves (64x64 per wave), K=1024 fixed.
// ---------------------------------------------------------------------------
template<int NSTRIDE, bool GATHER_A, bool RELU, bool FINAL>
__global__ __launch_bounds__(256)
void gemm_kernel(const u16* __restrict__ Abase, const u16* __restrict__ Wbase,
                 size_t wclass_stride, const float* __restrict__ bias_base,
                 int bias_stride, const int* __restrict__ offsets,
                 const int* __restrict__ rowidx, u16* __restrict__ Hout,
                 float* __restrict__ Fout)
{
    __shared__ u16 sA[128 * 32];   // [row][k] bf16, 8 KB
    __shared__ u16 sB[128 * 32];   // [n][k] bf16, 8 KB
    const int tid = threadIdx.x;
    const int m0 = blockIdx.x * 128;
    if (m0 >= offsets[CC]) return;            // beyond padded total
    int c = 0;
    while (m0 >= offsets[c + 1]) ++c;         // tile -> class (offsets are 128-multiples)
    const int n0 = blockIdx.y * 128;

    const int srow = tid >> 2;                // 0..63
    const int kc8 = (tid & 3) * 8;            // k-chunk (8 bf16 = 16B)
    int sa0 = m0 + srow, sa1 = m0 + srow + 64;
    if (GATHER_A) {
        const int g0 = rowidx[sa0]; sa0 = (g0 < 0) ? 0 : g0;
        const int g1 = rowidx[sa1]; sa1 = (g1 < 0) ? 0 : g1;
    }
    const u16* gA0 = Abase + (size_t)sa0 * 1024 + kc8;
    const u16* gA1 = Abase + (size_t)sa1 * 1024 + kc8;
    const u16* Wcl = Wbase + (size_t)c * wclass_stride;
    const u16* gB0 = Wcl + (size_t)(n0 + srow) * 1024 + kc8;
    const u16* gB1 = Wcl + (size_t)(n0 + srow + 64) * 1024 + kc8;
    u16* lA0 = sA + tid * 8;
    u16* lA1 = sA + 2048 + tid * 8;
    u16* lB0 = sB + tid * 8;
    u16* lB1 = sB + 2048 + tid * 8;

    const int lane = tid & 63, wv = tid >> 6;
    const int wm = (wv & 1) * 64, wn = (wv >> 1) * 64;
    const int lr = lane & 15, lg = lane >> 4;
    const u16* fA = sA + (wm + lr) * 32 + lg * 8;
    const u16* fB = sB + (wn + lr) * 32 + lg * 8;

    f32x4 acc[4][4];
    #pragma unroll
    for (int i = 0; i < 4; ++i)
        #pragma unroll
        for (int j = 0; j < 4; ++j)
            acc[i][j] = (f32x4){0.f, 0.f, 0.f, 0.f};

    for (int kt = 0; kt < 32; ++kt) {
        const int kb = kt * 32;
        GLDS16(gA0 + kb, lA0);
        GLDS16(gA1 + kb, lA1);
        GLDS16(gB0 + kb, lB0);
        GLDS16(gB1 + kb, lB1);
        __syncthreads();
        bf16x8 af[4], bfr[4];
        #pragma unroll
        for (int i = 0; i < 4; ++i) {
            af[i]  = *(const bf16x8*)(fA + i * 16 * 32);
            bfr[i] = *(const bf16x8*)(fB + i * 16 * 32);
        }
        #pragma unroll
        for (int mi = 0; mi < 4; ++mi)
            #pragma unroll
            for (int ni = 0; ni < 4; ++ni)
                acc[mi][ni] = __builtin_amdgcn_mfma_f32_16x16x32_bf16(
                    af[mi], bfr[ni], acc[mi][ni], 0, 0, 0);
        __syncthreads();
    }

    const float* bp = bias_base + (size_t)c * bias_stride + n0 + wn + lr;
    #pragma unroll
    for (int ni = 0; ni < 4; ++ni) {
        const float bv = bp[ni * 16];
        const int col = n0 + wn + ni * 16 + lr;
        #pragma unroll
        for (int mi = 0; mi < 4; ++mi) {
            const int rb = m0 + wm + mi * 16 + lg * 4;
            #pragma unroll
            for (int q = 0; q < 4; ++q) {
                float v = acc[mi][ni][q] + bv;
                if (RELU) v = v > 0.f ? v : 0.f;
                if (FINAL) {
                    const int orow = rowidx[rb + q];
                    if (orow >= 0) Fout[(size_t)orow * NSTRIDE + col] = v;
                } else {
                    Hout[(size_t)(rb + q) * NSTRIDE + col] = f2bf(v);
                }
            }
        }
    }
}

// ---------------------------------------------------------------------------
extern "C" void kernel_launch(void* const* d_in, const int* in_sizes, int n_in,
                              void* d_out, int out_size, void* d_ws, size_t ws_size,
                              hipStream_t stream)
{
    const float* x  = (const float*)d_in[0];
    const float* Wc = (const float*)d_in[1];
    const float* bc = (const float*)d_in[2];
    const float* W1 = (const float*)d_in[3];
    const float* b1 = (const float*)d_in[4];
    const float* W2 = (const float*)d_in[5];
    const float* b2 = (const float*)d_in[6];
    const float* Wo = (const float*)d_in[7];
    const float* bo = (const float*)d_in[8];
    float* out    = (float*)d_out;                 // [B][O]
    float* logits = out + (size_t)BB * OO;         // [B][C]

    char* ws = (char*)d_ws;
    constexpr size_t PADMAX = BB + CC * 128;       // 17408 padded rows max
    constexpr int NLB = BB / 16;                   // 1024 logits blocks
    int* offsets   = (int*)(ws + 0);               // [9]
    int* hist      = (int*)(ws + 64);              // [NLB][8]
    int* bb        = (int*)(ws + 64 + NLB * 32);   // [NLB][8]
    int* class_idx = (int*)(ws + 64 + 2 * NLB * 32);
    int* rowidx    = (int*)((char*)class_idx + (size_t)BB * 4);
    u16* x_bf16    = (u16*)((char*)rowidx + PADMAX * 4);
    u16* hA  = x_bf16 + (size_t)BB * DD;
    u16* hB  = hA + PADMAX * HH;
    u16* W1T = hB + PADMAX * HH;                    // [C][H][D]
    u16* W2T = W1T + (size_t)CC * DD * HH;          // [C][2][H][H]
    u16* WoT = W2T + (size_t)CC * 2 * HH * HH;      // [C][O][H]

    hipMemsetAsync(rowidx, 0xFF, PADMAX * 4, stream);  // pad slots = -1

    transpose_bf16_kernel<<<dim3(32, 32, 8),  256, 0, stream>>>(W1, W1T, DD, HH);
    transpose_bf16_kernel<<<dim3(32, 32, 16), 256, 0, stream>>>(W2, W2T, HH, HH);
    transpose_bf16_kernel<<<dim3(8, 32, 8),   256, 0, stream>>>(Wo, WoT, HH, OO);

    logits_kernel<<<NLB, 256, 0, stream>>>(x, Wc, bc, logits, x_bf16, class_idx, hist);
    scan_kernel<<<1, 256, 0, stream>>>(hist, offsets, bb);
    scatter_kernel<<<BB / 256, 256, 0, stream>>>(class_idx, bb, rowidx);

    constexpr int MT = BB / 128 + CC;  // 136 M-tiles (covers worst-case padding)
    gemm_kernel<HH, true,  true,  false><<<dim3(MT, 8), 256, 0, stream>>>(
        x_bf16, W1T, (size_t)DD * HH, b1, HH, offsets, rowidx, hA, nullptr);
    gemm_kernel<HH, false, true,  false><<<dim3(MT, 8), 256, 0, stream>>>(
        hA, W2T, (size_t)2 * HH * HH, b2, 2 * HH, offsets, rowidx, hB, nullptr);
    gemm_kernel<HH, false, true,  false><<<dim3(MT, 8), 256, 0, stream>>>(
        hB, W2T + (size_t)HH * HH, (size_t)2 * HH * HH, b2 + HH, 2 * HH, offsets, rowidx, hA, nullptr);
    gemm_kernel<OO, false, false, true ><<<dim3(MT, 2), 256, 0, stream>>>(
        hA, WoT, (size_t)OO * HH, bo, OO, offsets, rowidx, nullptr, out);
}

// Round 4
// 274.025 us; speedup vs baseline: 1.9991x; 1.0918x over previous
//
#include <hip/hip_runtime.h>
#include <stdint.h>

// Problem constants
#define BB 16384
#define DD 1024
#define HH 1024
#define OO 256
#define CC 8

typedef unsigned short u16;
typedef __attribute__((ext_vector_type(4))) unsigned short u16x4;
typedef __attribute__((ext_vector_type(8))) short bf16x8;
typedef __attribute__((ext_vector_type(4))) float f32x4;

__device__ __forceinline__ u16 f2bf(float f) {
    union { float f; uint32_t u; } v; v.f = f;
    const uint32_t u = v.u;
    return (u16)((u + 0x7FFFu + ((u >> 16) & 1u)) >> 16);  // RNE
}

// async global->LDS, 16B per lane (dest must be wave-uniform base + lane*16)
#define GLDS16(g, l)                                                                   \
    __builtin_amdgcn_global_load_lds((const __attribute__((address_space(1))) void*)(g), \
                                     (__attribute__((address_space(3))) void*)(l), 16, 0, 0)

// ---------------------------------------------------------------------------
// Transpose fp32 [nmat][R][Cc] -> bf16 [nmat][Cc][R]  (W -> W^T, K-contiguous)
// ---------------------------------------------------------------------------
__global__ __launch_bounds__(256)
void transpose_bf16_kernel(const float* __restrict__ src, u16* __restrict__ dst,
                           int R, int Cc)
{
    __shared__ float t[32][33];
    const int tid = threadIdx.x;
    const int mat = blockIdx.z;
    const int r0 = blockIdx.y * 32, c0 = blockIdx.x * 32;
    {
        const int rr = tid >> 3, c4 = (tid & 7) * 4;
        const float4 v = *(const float4*)(src + ((size_t)mat * R + r0 + rr) * Cc + c0 + c4);
        t[rr][c4 + 0] = v.x; t[rr][c4 + 1] = v.y; t[rr][c4 + 2] = v.z; t[rr][c4 + 3] = v.w;
    }
    __syncthreads();
    {
        const int cc = tid >> 3, k4 = (tid & 7) * 4;
        u16x4 o;
        o[0] = f2bf(t[k4 + 0][cc]);
        o[1] = f2bf(t[k4 + 1][cc]);
        o[2] = f2bf(t[k4 + 2][cc]);
        o[3] = f2bf(t[k4 + 3][cc]);
        *(u16x4*)(dst + ((size_t)mat * Cc + c0 + cc) * R + r0 + k4) = o;
    }
}

// ---------------------------------------------------------------------------
// Logits (fp32, exact routing) + x -> bf16 + per-block class histogram.
// (unchanged from R3 — fell out of top-5)
// ---------------------------------------------------------------------------
__global__ __launch_bounds__(256)
void logits_kernel(const float* __restrict__ x, const float* __restrict__ Wc,
                   const float* __restrict__ bc, float* __restrict__ logits_out,
                   u16* __restrict__ x_bf16, int* __restrict__ class_idx,
                   int* __restrict__ hist)
{
    __shared__ float WcT[CC][DD];  // 32 KB, transposed classifier
    __shared__ int clsarr[16];
    const int tid = threadIdx.x;
    #pragma unroll
    for (int j = 0; j < 8; ++j) {
        const int f = tid + 256 * j;                 // float4 index into Wc [D][C]
        const float4 v = ((const float4*)Wc)[f];
        const int d = f >> 1, c = (f & 1) * 4;       // 4 elems share d (C=8)
        WcT[c + 0][d] = v.x; WcT[c + 1][d] = v.y; WcT[c + 2][d] = v.z; WcT[c + 3][d] = v.w;
    }
    __syncthreads();

    const int lane = tid & 63, wv = tid >> 6;
    const int row0 = blockIdx.x * 16 + wv * 4;

    float acc[4][8];
    #pragma unroll
    for (int r = 0; r < 4; ++r)
        #pragma unroll
        for (int c = 0; c < 8; ++c) acc[r][c] = 0.f;

    #pragma unroll
    for (int p = 0; p < 2; ++p) {
        float4 xv[2][4];
        #pragma unroll
        for (int rr = 0; rr < 2; ++rr) {
            const float4* xr = (const float4*)(x + (size_t)(row0 + 2 * p + rr) * DD);
            #pragma unroll
            for (int j = 0; j < 4; ++j) xv[rr][j] = xr[lane + 64 * j];
        }
        #pragma unroll
        for (int rr = 0; rr < 2; ++rr) {
            u16* xb = x_bf16 + (size_t)(row0 + 2 * p + rr) * DD;
            #pragma unroll
            for (int j = 0; j < 4; ++j) {
                const float4 v = xv[rr][j];
                u16x4 o; o[0] = f2bf(v.x); o[1] = f2bf(v.y); o[2] = f2bf(v.z); o[3] = f2bf(v.w);
                *(u16x4*)(xb + 4 * (lane + 64 * j)) = o;
            }
        }
        #pragma unroll
        for (int j = 0; j < 4; ++j) {
            const int f = lane + 64 * j;
            #pragma unroll
            for (int c = 0; c < 8; ++c) {
                const float4 w = *(const float4*)&WcT[c][4 * f];
                #pragma unroll
                for (int rr = 0; rr < 2; ++rr)
                    acc[2 * p + rr][c] += xv[rr][j].x * w.x + xv[rr][j].y * w.y
                                        + xv[rr][j].z * w.z + xv[rr][j].w * w.w;
            }
        }
    }

    #pragma unroll
    for (int off = 8; off < 64; off <<= 1)
        #pragma unroll
        for (int r = 0; r < 4; ++r)
            #pragma unroll
            for (int c = 0; c < 8; ++c)
                acc[r][c] += __shfl_xor(acc[r][c], off, 64);

    const int cls = lane >> 3;
    const float bcv = bc[cls];
    float s[4];
    #pragma unroll
    for (int r = 0; r < 4; ++r) {
        float v = acc[r][0];
        #pragma unroll
        for (int c = 1; c < 8; ++c) v = (cls == c) ? acc[r][c] : v;
        s[r] = v;
    }
    #pragma unroll
    for (int off = 1; off < 8; off <<= 1)
        #pragma unroll
        for (int r = 0; r < 4; ++r) s[r] += __shfl_xor(s[r], off, 64);
    #pragma unroll
    for (int r = 0; r < 4; ++r) s[r] += bcv;

    #pragma unroll
    for (int r = 0; r < 4; ++r)
        if ((lane & 7) == 0) logits_out[(size_t)(row0 + r) * CC + cls] = s[r];

    int idx[4] = {cls, cls, cls, cls};
    #pragma unroll
    for (int off = 8; off < 64; off <<= 1) {
        #pragma unroll
        for (int r = 0; r < 4; ++r) {
            const float ov = __shfl_xor(s[r], off, 64);
            const int oi = __shfl_xor(idx[r], off, 64);
            const bool take = (ov > s[r]) || (ov == s[r] && oi < idx[r]);
            s[r] = take ? ov : s[r];
            idx[r] = take ? oi : idx[r];
        }
    }
    if (lane == 0) {
        #pragma unroll
        for (int r = 0; r < 4; ++r) {
            class_idx[row0 + r] = idx[r];
            clsarr[wv * 4 + r] = idx[r];
        }
    }
    __syncthreads();
    if (tid < 64) {
        const int myc = (tid < 16) ? clsarr[tid] : -1;
        int h = 0;
        #pragma unroll
        for (int cc = 0; cc < 8; ++cc) {
            const int p = __popcll(__ballot(myc == cc));
            h = (tid == cc) ? p : h;
        }
        if (tid < 8) hist[blockIdx.x * 8 + tid] = h;
    }
}

// ---------------------------------------------------------------------------
// Single-block scan: per-class totals -> padded offsets + per-block bases.
// ---------------------------------------------------------------------------
__global__ __launch_bounds__(256)
void scan_kernel(const int* __restrict__ hist, int* __restrict__ offsets,
                 int* __restrict__ bb)
{
    const int t = threadIdx.x, c = t >> 5, g = t & 31;
    int sum = 0;
    #pragma unroll 4
    for (int i = 0; i < 32; ++i) sum += hist[(g * 32 + i) * 8 + c];
    int inc = sum;
    #pragma unroll
    for (int d = 1; d < 32; d <<= 1) {
        const int v = __shfl_up(inc, d, 32);
        if (g >= d) inc += v;
    }
    __shared__ int tot[8], offL[9];
    if (g == 31) tot[c] = inc;
    __syncthreads();
    if (t == 0) {
        int o = 0; offL[0] = 0; offsets[0] = 0;
        #pragma unroll
        for (int c8 = 0; c8 < 8; ++c8) {
            o += (tot[c8] + 127) & ~127;
            offL[c8 + 1] = o; offsets[c8 + 1] = o;
        }
    }
    __syncthreads();
    int base = offL[c] + (inc - sum);
    #pragma unroll 4
    for (int i = 0; i < 32; ++i) {
        const int b = g * 32 + i;
        bb[b * 8 + c] = base;
        base += hist[b * 8 + c];
    }
}

// ---------------------------------------------------------------------------
// Scatter row ids into per-class segments — atomic-free via ballot ranking.
// ---------------------------------------------------------------------------
__global__ __launch_bounds__(256)
void scatter_kernel(const int* __restrict__ class_idx, const int* __restrict__ bb,
                    int* __restrict__ rowidx)
{
    const int r = blockIdx.x * 256 + threadIdx.x;
    const int c = class_idx[r];
    const int lane = threadIdx.x & 63;
    const int gl = lane & ~15;
    const unsigned long long before = (1ull << lane) - (1ull << gl);
    int rank = 0;
    #pragma unroll
    for (int cc = 0; cc < 8; ++cc) {
        const unsigned long long m = __ballot(c == cc);
        const int p = __popcll(m & before);
        rank = (c == cc) ? p : rank;
    }
    rowidx[bb[(r >> 4) * 8 + c] + rank] = r;
}

// ---------------------------------------------------------------------------
// Routed GEMM: out[m][n] = act(A[m][:] . W_c[:][n] + bias_c[n])
// BM=BN=128, BK=32, 256 threads / 4 waves (64x64 per wave), K=1024 fixed.
// R4: (1) double-buffered LDS + prefetch-next-tile-before-compute ("minimum
// 2-phase", T3 recipe) so load latency hides under ds_read+MFMA; (2) 1-D grid
// with bijective XCD-chunked swizzle, n0-inner: 8/2 consecutive wgs share one
// A-tile on the same XCD L2, per-XCD working set (~2 MB B-panel) L2-resident.
// ---------------------------------------------------------------------------
#define STAGE(b, kt)                            \
    {                                           \
        const int kb_ = (kt) * 32;              \
        GLDS16(gA0 + kb_, lA0 + (b) * 4096);    \
        GLDS16(gA1 + kb_, lA1 + (b) * 4096);    \
        GLDS16(gB0 + kb_, lB0 + (b) * 4096);    \
        GLDS16(gB1 + kb_, lB1 + (b) * 4096);    \
    }

#define COMPUTE(b)                                                        \
    {                                                                     \
        bf16x8 af[4], bfr[4];                                             \
        _Pragma("unroll")                                                 \
        for (int i = 0; i < 4; ++i) {                                     \
            af[i]  = *(const bf16x8*)(fA + (b) * 4096 + i * 16 * 32);     \
            bfr[i] = *(const bf16x8*)(fB + (b) * 4096 + i * 16 * 32);     \
        }                                                                 \
        _Pragma("unroll")                                                 \
        for (int mi = 0; mi < 4; ++mi)                                    \
            _Pragma("unroll")                                             \
            for (int ni = 0; ni < 4; ++ni)                                \
                acc[mi][ni] = __builtin_amdgcn_mfma_f32_16x16x32_bf16(    \
                    af[mi], bfr[ni], acc[mi][ni], 0, 0, 0);               \
    }

template<int NT_Y, int NSTRIDE, bool GATHER_A, bool RELU, bool FINAL>
__global__ __launch_bounds__(256)
void gemm_kernel(const u16* __restrict__ Abase, const u16* __restrict__ Wbase,
                 size_t wclass_stride, const float* __restrict__ bias_base,
                 int bias_stride, const int* __restrict__ offsets,
                 const int* __restrict__ rowidx, u16* __restrict__ Hout,
                 float* __restrict__ Fout)
{
    __shared__ u16 sA[2 * 128 * 32];   // [buf][row][k] bf16, 2 x 8 KB
    __shared__ u16 sB[2 * 128 * 32];
    const int tid = threadIdx.x;

    // bijective XCD-chunked swizzle (nwg % 8 == 0), n0 inner
    const int bid = blockIdx.x;
    const int wg = (bid & 7) * ((int)gridDim.x >> 3) + (bid >> 3);
    const int m0 = (wg / NT_Y) * 128;
    const int n0 = (wg % NT_Y) * 128;
    if (m0 >= offsets[CC]) return;            // beyond padded total
    int c = 0;
    while (m0 >= offsets[c + 1]) ++c;         // tile -> class (offsets are 128-multiples)

    const int srow = tid >> 2;                // 0..63
    const int kc8 = (tid & 3) * 8;            // k-chunk (8 bf16 = 16B)
    int sa0 = m0 + srow, sa1 = m0 + srow + 64;
    if (GATHER_A) {
        const int g0 = rowidx[sa0]; sa0 = (g0 < 0) ? 0 : g0;
        const int g1 = rowidx[sa1]; sa1 = (g1 < 0) ? 0 : g1;
    }
    const u16* gA0 = Abase + (size_t)sa0 * 1024 + kc8;
    const u16* gA1 = Abase + (size_t)sa1 * 1024 + kc8;
    const u16* Wcl = Wbase + (size_t)c * wclass_stride;
    const u16* gB0 = Wcl + (size_t)(n0 + srow) * 1024 + kc8;
    const u16* gB1 = Wcl + (size_t)(n0 + srow + 64) * 1024 + kc8;
    u16* lA0 = sA + tid * 8;
    u16* lA1 = sA + 2048 + tid * 8;
    u16* lB0 = sB + tid * 8;
    u16* lB1 = sB + 2048 + tid * 8;

    const int lane = tid & 63, wv = tid >> 6;
    const int wm = (wv & 1) * 64, wn = (wv >> 1) * 64;
    const int lr = lane & 15, lg = lane >> 4;
    const u16* fA = sA + (wm + lr) * 32 + lg * 8;
    const u16* fB = sB + (wn + lr) * 32 + lg * 8;

    f32x4 acc[4][4];
    #pragma unroll
    for (int i = 0; i < 4; ++i)
        #pragma unroll
        for (int j = 0; j < 4; ++j)
            acc[i][j] = (f32x4){0.f, 0.f, 0.f, 0.f};

    // prologue: tile 0 into buf 0
    STAGE(0, 0);
    __syncthreads();
    // main: prefetch t+1 into other buf BEFORE computing t (latency hides
    // under ds_read+MFMA; barrier pays only the residual)
    for (int kt = 0; kt < 31; ++kt) {
        if (kt & 1) { STAGE(0, kt + 1); COMPUTE(1); }
        else        { STAGE(1, kt + 1); COMPUTE(0); }
        __syncthreads();
    }
    COMPUTE(1);   // tile 31

    const float* bp = bias_base + (size_t)c * bias_stride + n0 + wn + lr;
    #pragma unroll
    for (int ni = 0; ni < 4; ++ni) {
        const float bv = bp[ni * 16];
        const int col = n0 + wn + ni * 16 + lr;
        #pragma unroll
        for (int mi = 0; mi < 4; ++mi) {
            const int rb = m0 + wm + mi * 16 + lg * 4;
            #pragma unroll
            for (int q = 0; q < 4; ++q) {
                float v = acc[mi][ni][q] + bv;
                if (RELU) v = v > 0.f ? v : 0.f;
                if (FINAL) {
                    const int orow = rowidx[rb + q];
                    if (orow >= 0) Fout[(size_t)orow * NSTRIDE + col] = v;
                } else {
                    Hout[(size_t)(rb + q) * NSTRIDE + col] = f2bf(v);
                }
            }
        }
    }
}

// ---------------------------------------------------------------------------
extern "C" void kernel_launch(void* const* d_in, const int* in_sizes, int n_in,
                              void* d_out, int out_size, void* d_ws, size_t ws_size,
                              hipStream_t stream)
{
    const float* x  = (const float*)d_in[0];
    const float* Wc = (const float*)d_in[1];
    const float* bc = (const float*)d_in[2];
    const float* W1 = (const float*)d_in[3];
    const float* b1 = (const float*)d_in[4];
    const float* W2 = (const float*)d_in[5];
    const float* b2 = (const float*)d_in[6];
    const float* Wo = (const float*)d_in[7];
    const float* bo = (const float*)d_in[8];
    float* out    = (float*)d_out;                 // [B][O]
    float* logits = out + (size_t)BB * OO;         // [B][C]

    char* ws = (char*)d_ws;
    constexpr size_t PADMAX = BB + CC * 128;       // 17408 padded rows max
    constexpr int NLB = BB / 16;                   // 1024 logits blocks
    int* offsets   = (int*)(ws + 0);               // [9]
    int* hist      = (int*)(ws + 64);              // [NLB][8]
    int* bb        = (int*)(ws + 64 + NLB * 32);   // [NLB][8]
    int* class_idx = (int*)(ws + 64 + 2 * NLB * 32);
    int* rowidx    = (int*)((char*)class_idx + (size_t)BB * 4);
    u16* x_bf16    = (u16*)((char*)rowidx + PADMAX * 4);
    u16* hA  = x_bf16 + (size_t)BB * DD;
    u16* hB  = hA + PADMAX * HH;
    u16* W1T = hB + PADMAX * HH;                    // [C][H][D]
    u16* W2T = W1T + (size_t)CC * DD * HH;          // [C][2][H][H]
    u16* WoT = W2T + (size_t)CC * 2 * HH * HH;      // [C][O][H]

    hipMemsetAsync(rowidx, 0xFF, PADMAX * 4, stream);  // pad slots = -1

    transpose_bf16_kernel<<<dim3(32, 32, 8),  256, 0, stream>>>(W1, W1T, DD, HH);
    transpose_bf16_kernel<<<dim3(32, 32, 16), 256, 0, stream>>>(W2, W2T, HH, HH);
    transpose_bf16_kernel<<<dim3(8, 32, 8),   256, 0, stream>>>(Wo, WoT, HH, OO);

    logits_kernel<<<NLB, 256, 0, stream>>>(x, Wc, bc, logits, x_bf16, class_idx, hist);
    scan_kernel<<<1, 256, 0, stream>>>(hist, offsets, bb);
    scatter_kernel<<<BB / 256, 256, 0, stream>>>(class_idx, bb, rowidx);

    constexpr int MT = BB / 128 + CC;  // 136 M-tiles (covers worst-case padding)
    gemm_kernel<8, HH, true,  true,  false><<<dim3(MT * 8), 256, 0, stream>>>(
        x_bf16, W1T, (size_t)DD * HH, b1, HH, offsets, rowidx, hA, nullptr);
    gemm_kernel<8, HH, false, true,  false><<<dim3(MT * 8), 256, 0, stream>>>(
        hA, W2T, (size_t)2 * HH * HH, b2, 2 * HH, offsets, rowidx, hB, nullptr);
    gemm_kernel<8, HH, false, true,  false><<<dim3(MT * 8), 256, 0, stream>>>(
        hB, W2T + (size_t)HH * HH, (size_t)2 * HH * HH, b2 + HH, 2 * HH, offsets, rowidx, hA, nullptr);
    gemm_kernel<2, OO, false, false, true ><<<dim3(MT * 2), 256, 0, stream>>>(
        hA, WoT, (size_t)OO * HH, bo, OO, offsets, rowidx, nullptr, out);
}

// Round 5
// 273.774 us; speedup vs baseline: 2.0010x; 1.0009x over previous
//
#include <hip/hip_runtime.h>
#include <stdint.h>

// Problem constants
#define BB 16384
#define DD 1024
#define HH 1024
#define OO 256
#define CC 8

typedef unsigned short u16;
typedef __attribute__((ext_vector_type(4))) unsigned short u16x4;
typedef __attribute__((ext_vector_type(8))) short bf16x8;
typedef __attribute__((ext_vector_type(4))) float f32x4;

__device__ __forceinline__ u16 f2bf(float f) {
    union { float f; uint32_t u; } v; v.f = f;
    const uint32_t u = v.u;
    return (u16)((u + 0x7FFFu + ((u >> 16) & 1u)) >> 16);  // RNE
}

// async global->LDS, 16B per lane (dest must be wave-uniform base + lane*16)
#define GLDS16(g, l)                                                                   \
    __builtin_amdgcn_global_load_lds((const __attribute__((address_space(1))) void*)(g), \
                                     (__attribute__((address_space(3))) void*)(l), 16, 0, 0)

// ---------------------------------------------------------------------------
// Transpose fp32 [nmat][R][Cc] -> bf16 [nmat][Cc][R]  (W -> W^T, K-contiguous)
// ---------------------------------------------------------------------------
__global__ __launch_bounds__(256)
void transpose_bf16_kernel(const float* __restrict__ src, u16* __restrict__ dst,
                           int R, int Cc)
{
    __shared__ float t[32][33];
    const int tid = threadIdx.x;
    const int mat = blockIdx.z;
    const int r0 = blockIdx.y * 32, c0 = blockIdx.x * 32;
    {
        const int rr = tid >> 3, c4 = (tid & 7) * 4;
        const float4 v = *(const float4*)(src + ((size_t)mat * R + r0 + rr) * Cc + c0 + c4);
        t[rr][c4 + 0] = v.x; t[rr][c4 + 1] = v.y; t[rr][c4 + 2] = v.z; t[rr][c4 + 3] = v.w;
    }
    __syncthreads();
    {
        const int cc = tid >> 3, k4 = (tid & 7) * 4;
        u16x4 o;
        o[0] = f2bf(t[k4 + 0][cc]);
        o[1] = f2bf(t[k4 + 1][cc]);
        o[2] = f2bf(t[k4 + 2][cc]);
        o[3] = f2bf(t[k4 + 3][cc]);
        *(u16x4*)(dst + ((size_t)mat * Cc + c0 + cc) * R + r0 + k4) = o;
    }
}

// ---------------------------------------------------------------------------
// Logits (fp32, exact routing) + x -> bf16 + per-block class histogram.
// (unchanged — out of top-5 since R3)
// ---------------------------------------------------------------------------
__global__ __launch_bounds__(256)
void logits_kernel(const float* __restrict__ x, const float* __restrict__ Wc,
                   const float* __restrict__ bc, float* __restrict__ logits_out,
                   u16* __restrict__ x_bf16, int* __restrict__ class_idx,
                   int* __restrict__ hist)
{
    __shared__ float WcT[CC][DD];  // 32 KB, transposed classifier
    __shared__ int clsarr[16];
    const int tid = threadIdx.x;
    #pragma unroll
    for (int j = 0; j < 8; ++j) {
        const int f = tid + 256 * j;                 // float4 index into Wc [D][C]
        const float4 v = ((const float4*)Wc)[f];
        const int d = f >> 1, c = (f & 1) * 4;       // 4 elems share d (C=8)
        WcT[c + 0][d] = v.x; WcT[c + 1][d] = v.y; WcT[c + 2][d] = v.z; WcT[c + 3][d] = v.w;
    }
    __syncthreads();

    const int lane = tid & 63, wv = tid >> 6;
    const int row0 = blockIdx.x * 16 + wv * 4;

    float acc[4][8];
    #pragma unroll
    for (int r = 0; r < 4; ++r)
        #pragma unroll
        for (int c = 0; c < 8; ++c) acc[r][c] = 0.f;

    #pragma unroll
    for (int p = 0; p < 2; ++p) {
        float4 xv[2][4];
        #pragma unroll
        for (int rr = 0; rr < 2; ++rr) {
            const float4* xr = (const float4*)(x + (size_t)(row0 + 2 * p + rr) * DD);
            #pragma unroll
            for (int j = 0; j < 4; ++j) xv[rr][j] = xr[lane + 64 * j];
        }
        #pragma unroll
        for (int rr = 0; rr < 2; ++rr) {
            u16* xb = x_bf16 + (size_t)(row0 + 2 * p + rr) * DD;
            #pragma unroll
            for (int j = 0; j < 4; ++j) {
                const float4 v = xv[rr][j];
                u16x4 o; o[0] = f2bf(v.x); o[1] = f2bf(v.y); o[2] = f2bf(v.z); o[3] = f2bf(v.w);
                *(u16x4*)(xb + 4 * (lane + 64 * j)) = o;
            }
        }
        #pragma unroll
        for (int j = 0; j < 4; ++j) {
            const int f = lane + 64 * j;
            #pragma unroll
            for (int c = 0; c < 8; ++c) {
                const float4 w = *(const float4*)&WcT[c][4 * f];
                #pragma unroll
                for (int rr = 0; rr < 2; ++rr)
                    acc[2 * p + rr][c] += xv[rr][j].x * w.x + xv[rr][j].y * w.y
                                        + xv[rr][j].z * w.z + xv[rr][j].w * w.w;
            }
        }
    }

    #pragma unroll
    for (int off = 8; off < 64; off <<= 1)
        #pragma unroll
        for (int r = 0; r < 4; ++r)
            #pragma unroll
            for (int c = 0; c < 8; ++c)
                acc[r][c] += __shfl_xor(acc[r][c], off, 64);

    const int cls = lane >> 3;
    const float bcv = bc[cls];
    float s[4];
    #pragma unroll
    for (int r = 0; r < 4; ++r) {
        float v = acc[r][0];
        #pragma unroll
        for (int c = 1; c < 8; ++c) v = (cls == c) ? acc[r][c] : v;
        s[r] = v;
    }
    #pragma unroll
    for (int off = 1; off < 8; off <<= 1)
        #pragma unroll
        for (int r = 0; r < 4; ++r) s[r] += __shfl_xor(s[r], off, 64);
    #pragma unroll
    for (int r = 0; r < 4; ++r) s[r] += bcv;

    #pragma unroll
    for (int r = 0; r < 4; ++r)
        if ((lane & 7) == 0) logits_out[(size_t)(row0 + r) * CC + cls] = s[r];

    int idx[4] = {cls, cls, cls, cls};
    #pragma unroll
    for (int off = 8; off < 64; off <<= 1) {
        #pragma unroll
        for (int r = 0; r < 4; ++r) {
            const float ov = __shfl_xor(s[r], off, 64);
            const int oi = __shfl_xor(idx[r], off, 64);
            const bool take = (ov > s[r]) || (ov == s[r] && oi < idx[r]);
            s[r] = take ? ov : s[r];
            idx[r] = take ? oi : idx[r];
        }
    }
    if (lane == 0) {
        #pragma unroll
        for (int r = 0; r < 4; ++r) {
            class_idx[row0 + r] = idx[r];
            clsarr[wv * 4 + r] = idx[r];
        }
    }
    __syncthreads();
    if (tid < 64) {
        const int myc = (tid < 16) ? clsarr[tid] : -1;
        int h = 0;
        #pragma unroll
        for (int cc = 0; cc < 8; ++cc) {
            const int p = __popcll(__ballot(myc == cc));
            h = (tid == cc) ? p : h;
        }
        if (tid < 8) hist[blockIdx.x * 8 + tid] = h;
    }
}

// ---------------------------------------------------------------------------
// Single-block scan: per-class totals -> padded offsets + per-block bases.
// ---------------------------------------------------------------------------
__global__ __launch_bounds__(256)
void scan_kernel(const int* __restrict__ hist, int* __restrict__ offsets,
                 int* __restrict__ bb)
{
    const int t = threadIdx.x, c = t >> 5, g = t & 31;
    int sum = 0;
    #pragma unroll 4
    for (int i = 0; i < 32; ++i) sum += hist[(g * 32 + i) * 8 + c];
    int inc = sum;
    #pragma unroll
    for (int d = 1; d < 32; d <<= 1) {
        const int v = __shfl_up(inc, d, 32);
        if (g >= d) inc += v;
    }
    __shared__ int tot[8], offL[9];
    if (g == 31) tot[c] = inc;
    __syncthreads();
    if (t == 0) {
        int o = 0; offL[0] = 0; offsets[0] = 0;
        #pragma unroll
        for (int c8 = 0; c8 < 8; ++c8) {
            o += (tot[c8] + 127) & ~127;
            offL[c8 + 1] = o; offsets[c8 + 1] = o;
        }
    }
    __syncthreads();
    int base = offL[c] + (inc - sum);
    #pragma unroll 4
    for (int i = 0; i < 32; ++i) {
        const int b = g * 32 + i;
        bb[b * 8 + c] = base;
        base += hist[b * 8 + c];
    }
}

// ---------------------------------------------------------------------------
// Scatter row ids into per-class segments — atomic-free via ballot ranking.
// ---------------------------------------------------------------------------
__global__ __launch_bounds__(256)
void scatter_kernel(const int* __restrict__ class_idx, const int* __restrict__ bb,
                    int* __restrict__ rowidx)
{
    const int r = blockIdx.x * 256 + threadIdx.x;
    const int c = class_idx[r];
    const int lane = threadIdx.x & 63;
    const int gl = lane & ~15;
    const unsigned long long before = (1ull << lane) - (1ull << gl);
    int rank = 0;
    #pragma unroll
    for (int cc = 0; cc < 8; ++cc) {
        const unsigned long long m = __ballot(c == cc);
        const int p = __popcll(m & before);
        rank = (c == cc) ? p : rank;
    }
    rowidx[bb[(r >> 4) * 8 + c] + rank] = r;
}

// ---------------------------------------------------------------------------
// Routed GEMM: out[m][n] = act(A[m][:] . W_c[:][n] + bias_c[n])
// BM=BN=128, BK=32, 256 threads / 4 waves (64x64 per wave), K=1024 fixed.
// R5: T4 counted-vmcnt pipeline — 3 LDS buffers (48 KB -> 3 blocks/CU),
// depth-2 prefetch, raw s_barrier + inline-asm s_waitcnt vmcnt(4) (NEVER 0
// in main loop), one barrier per K-step, T5 setprio around MFMA cluster.
// Overwrite-safety: STAGE into buf b at step s happens after the barrier all
// waves reached by finishing COMPUTE(b) at step s-1.
// Steady state: 2 tiles x 4 loads in flight -> vmcnt(4) drains oldest tile.
// ---------------------------------------------------------------------------
#define STAGE(b, kt)                            \
    {                                           \
        const int kb_ = (kt) * 32;              \
        GLDS16(gA0 + kb_, lA0 + (b) * 4096);    \
        GLDS16(gA1 + kb_, lA1 + (b) * 4096);    \
        GLDS16(gB0 + kb_, lB0 + (b) * 4096);    \
        GLDS16(gB1 + kb_, lB1 + (b) * 4096);    \
    }

#define COMPUTE(b)                                                        \
    {                                                                     \
        bf16x8 af[4], bfr[4];                                             \
        _Pragma("unroll")                                                 \
        for (int i = 0; i < 4; ++i) {                                     \
            af[i]  = *(const bf16x8*)(fA + (b) * 4096 + i * 16 * 32);     \
            bfr[i] = *(const bf16x8*)(fB + (b) * 4096 + i * 16 * 32);     \
        }                                                                 \
        __builtin_amdgcn_s_setprio(1);                                    \
        _Pragma("unroll")                                                 \
        for (int mi = 0; mi < 4; ++mi)                                    \
            _Pragma("unroll")                                             \
            for (int ni = 0; ni < 4; ++ni)                                \
                acc[mi][ni] = __builtin_amdgcn_mfma_f32_16x16x32_bf16(    \
                    af[mi], bfr[ni], acc[mi][ni], 0, 0, 0);               \
        __builtin_amdgcn_s_setprio(0);                                    \
    }

#define WAITV(N)                                                          \
    asm volatile("s_waitcnt vmcnt(" #N ")" ::: "memory");                 \
    __builtin_amdgcn_s_barrier();                                         \
    __builtin_amdgcn_sched_barrier(0);

template<int NT_Y, int NSTRIDE, bool GATHER_A, bool RELU, bool FINAL>
__global__ __launch_bounds__(256, 3)
void gemm_kernel(const u16* __restrict__ Abase, const u16* __restrict__ Wbase,
                 size_t wclass_stride, const float* __restrict__ bias_base,
                 int bias_stride, const int* __restrict__ offsets,
                 const int* __restrict__ rowidx, u16* __restrict__ Hout,
                 float* __restrict__ Fout)
{
    __shared__ u16 sA[3 * 128 * 32];   // [buf][row][k] bf16, 3 x 8 KB
    __shared__ u16 sB[3 * 128 * 32];
    const int tid = threadIdx.x;

    // bijective XCD-chunked swizzle (nwg % 8 == 0), n0 inner
    const int bid = blockIdx.x;
    const int wg = (bid & 7) * ((int)gridDim.x >> 3) + (bid >> 3);
    const int m0 = (wg / NT_Y) * 128;
    const int n0 = (wg % NT_Y) * 128;
    if (m0 >= offsets[CC]) return;            // beyond padded total (block-uniform)
    int c = 0;
    while (m0 >= offsets[c + 1]) ++c;         // tile -> class (offsets are 128-multiples)

    const int srow = tid >> 2;                // 0..63
    const int kc8 = (tid & 3) * 8;            // k-chunk (8 bf16 = 16B)
    int sa0 = m0 + srow, sa1 = m0 + srow + 64;
    if (GATHER_A) {
        const int g0 = rowidx[sa0]; sa0 = (g0 < 0) ? 0 : g0;
        const int g1 = rowidx[sa1]; sa1 = (g1 < 0) ? 0 : g1;
    }
    const u16* gA0 = Abase + (size_t)sa0 * 1024 + kc8;
    const u16* gA1 = Abase + (size_t)sa1 * 1024 + kc8;
    const u16* Wcl = Wbase + (size_t)c * wclass_stride;
    const u16* gB0 = Wcl + (size_t)(n0 + srow) * 1024 + kc8;
    const u16* gB1 = Wcl + (size_t)(n0 + srow + 64) * 1024 + kc8;
    u16* lA0 = sA + tid * 8;
    u16* lA1 = sA + 2048 + tid * 8;
    u16* lB0 = sB + tid * 8;
    u16* lB1 = sB + 2048 + tid * 8;

    const int lane = tid & 63, wv = tid >> 6;
    const int wm = (wv & 1) * 64, wn = (wv >> 1) * 64;
    const int lr = lane & 15, lg = lane >> 4;
    const u16* fA = sA + (wm + lr) * 32 + lg * 8;
    const u16* fB = sB + (wn + lr) * 32 + lg * 8;

    f32x4 acc[4][4];
    #pragma unroll
    for (int i = 0; i < 4; ++i)
        #pragma unroll
        for (int j = 0; j < 4; ++j)
            acc[i][j] = (f32x4){0.f, 0.f, 0.f, 0.f};

    // prologue: depth-2 prefetch (8 loads in flight per thread)
    STAGE(0, 0);
    STAGE(1, 1);
    // main loop: 30 steps, unrolled x3 so buffer ids are compile-time
    for (int kt = 0; kt < 30; kt += 3) {
        WAITV(4);               // tile kt landed (everyone's, after barrier)
        STAGE(2, kt + 2);
        COMPUTE(0);
        WAITV(4);
        STAGE(0, kt + 3);
        COMPUTE(1);
        WAITV(4);
        STAGE(1, kt + 4);
        COMPUTE(2);
    }
    // kt=30: tiles 30,31 in flight
    WAITV(4);
    COMPUTE(0);
    // kt=31: tile 31 in flight
    WAITV(0);
    COMPUTE(1);

    const float* bp = bias_base + (size_t)c * bias_stride + n0 + wn + lr;
    #pragma unroll
    for (int ni = 0; ni < 4; ++ni) {
        const float bv = bp[ni * 16];
        const int col = n0 + wn + ni * 16 + lr;
        #pragma unroll
        for (int mi = 0; mi < 4; ++mi) {
            const int rb = m0 + wm + mi * 16 + lg * 4;
            #pragma unroll
            for (int q = 0; q < 4; ++q) {
                float v = acc[mi][ni][q] + bv;
                if (RELU) v = v > 0.f ? v : 0.f;
                if (FINAL) {
                    const int orow = rowidx[rb + q];
                    if (orow >= 0) Fout[(size_t)orow * NSTRIDE + col] = v;
                } else {
                    Hout[(size_t)(rb + q) * NSTRIDE + col] = f2bf(v);
                }
            }
        }
    }
}

// ---------------------------------------------------------------------------
extern "C" void kernel_launch(void* const* d_in, const int* in_sizes, int n_in,
                              void* d_out, int out_size, void* d_ws, size_t ws_size,
                              hipStream_t stream)
{
    const float* x  = (const float*)d_in[0];
    const float* Wc = (const float*)d_in[1];
    const float* bc = (const float*)d_in[2];
    const float* W1 = (const float*)d_in[3];
    const float* b1 = (const float*)d_in[4];
    const float* W2 = (const float*)d_in[5];
    const float* b2 = (const float*)d_in[6];
    const float* Wo = (const float*)d_in[7];
    const float* bo = (const float*)d_in[8];
    float* out    = (float*)d_out;                 // [B][O]
    float* logits = out + (size_t)BB * OO;         // [B][C]

    char* ws = (char*)d_ws;
    constexpr size_t PADMAX = BB + CC * 128;       // 17408 padded rows max
    constexpr int NLB = BB / 16;                   // 1024 logits blocks
    int* offsets   = (int*)(ws + 0);               // [9]
    int* hist      = (int*)(ws + 64);              // [NLB][8]
    int* bb        = (int*)(ws + 64 + NLB * 32);   // [NLB][8]
    int* class_idx = (int*)(ws + 64 + 2 * NLB * 32);
    int* rowidx    = (int*)((char*)class_idx + (size_t)BB * 4);
    u16* x_bf16    = (u16*)((char*)rowidx + PADMAX * 4);
    u16* hA  = x_bf16 + (size_t)BB * DD;
    u16* hB  = hA + PADMAX * HH;
    u16* W1T = hB + PADMAX * HH;                    // [C][H][D]
    u16* W2T = W1T + (size_t)CC * DD * HH;          // [C][2][H][H]
    u16* WoT = W2T + (size_t)CC * 2 * HH * HH;      // [C][O][H]

    hipMemsetAsync(rowidx, 0xFF, PADMAX * 4, stream);  // pad slots = -1

    transpose_bf16_kernel<<<dim3(32, 32, 8),  256, 0, stream>>>(W1, W1T, DD, HH);
    transpose_bf16_kernel<<<dim3(32, 32, 16), 256, 0, stream>>>(W2, W2T, HH, HH);
    transpose_bf16_kernel<<<dim3(8, 32, 8),   256, 0, stream>>>(Wo, WoT, HH, OO);

    logits_kernel<<<NLB, 256, 0, stream>>>(x, Wc, bc, logits, x_bf16, class_idx, hist);
    scan_kernel<<<1, 256, 0, stream>>>(hist, offsets, bb);
    scatter_kernel<<<BB / 256, 256, 0, stream>>>(class_idx, bb, rowidx);

    constexpr int MT = BB / 128 + CC;  // 136 M-tiles (covers worst-case padding)
    gemm_kernel<8, HH, true,  true,  false><<<dim3(MT * 8), 256, 0, stream>>>(
        x_bf16, W1T, (size_t)DD * HH, b1, HH, offsets, rowidx, hA, nullptr);
    gemm_kernel<8, HH, false, true,  false><<<dim3(MT * 8), 256, 0, stream>>>(
        hA, W2T, (size_t)2 * HH * HH, b2, 2 * HH, offsets, rowidx, hB, nullptr);
    gemm_kernel<8, HH, false, true,  false><<<dim3(MT * 8), 256, 0, stream>>>(
        hB, W2T + (size_t)HH * HH, (size_t)2 * HH * HH, b2 + HH, 2 * HH, offsets, rowidx, hA, nullptr);
    gemm_kernel<2, OO, false, false, true ><<<dim3(MT * 2), 256, 0, stream>>>(
        hA, WoT, (size_t)OO * HH, bo, OO, offsets, rowidx, nullptr, out);
}